// Round 11
// baseline (274.878 us; speedup 1.0000x reference)
//
#include <hip/hip_runtime.h>
#include <math.h>

// Problem constants (match reference)
#define B_    2
#define T_    2048
#define C_    1024
#define HS_   8
#define DS_   32
#define HL_   8
#define DL_   128
#define HD_   64
#define WINS_ 256
#define WINL_ 1024
#define NALL_ 3584   // 512 (qk_s) + 512 (v_s) + 2048 (qk_l) + 512 (v_l)

typedef __bf16 bf16x8 __attribute__((ext_vector_type(8)));
typedef float floatx4 __attribute__((ext_vector_type(4)));

__device__ __forceinline__ ushort f2bf(float f) {
    union { float f; unsigned u; } v; v.f = f;
    unsigned r = v.u + 0x7fff + ((v.u >> 16) & 1);  // RNE
    return (ushort)(r >> 16);
}
__device__ __forceinline__ float bf2f(ushort u) {
    union { unsigned u; float f; } v; v.u = ((unsigned)u) << 16;
    return v.f;
}

// async global->LDS, 16B per lane. LDS dest = wave-uniform base + lane*16.
__device__ __forceinline__ void gload_lds16(const void* g, void* l) {
    __builtin_amdgcn_global_load_lds(
        (const __attribute__((address_space(1))) void*)g,
        (__attribute__((address_space(3))) void*)l, 16, 0, 0);
}

// ---------------------------------------------------------------------------
// Fused prep: blocks [0,4096) convert x fp32->bf16; blocks [4096,8704)
// transpose+convert the five weight matrices (K=1024 each).
// ---------------------------------------------------------------------------
__global__ __launch_bounds__(256) void prep(
    const float* __restrict__ x, ushort* __restrict__ x16,
    const float* __restrict__ Wqk_s, const float* __restrict__ Wv_s,
    const float* __restrict__ Wqk_l, const float* __restrict__ Wv_l,
    const float* __restrict__ Wproj, ushort* __restrict__ WallT,
    ushort* __restrict__ WprojT) {
    __shared__ float t[32][33];
    int bid = blockIdx.x;
    if (bid < 4096) {
        const int i = bid * 256 + threadIdx.x;
        float4 v = ((const float4*)x)[i];
        ushort4 o;
        o.x = f2bf(v.x); o.y = f2bf(v.y); o.z = f2bf(v.z); o.w = f2bf(v.w);
        ((ushort4*)x16)[i] = o;
        return;
    }
    bid -= 4096;
    const float* W; ushort* WT; int N, rowoff;
    if (bid < 512)       { W = Wqk_s; WT = WallT;  N = 512;  rowoff = 0; }
    else if (bid < 1024) { bid -= 512;  W = Wv_s;  WT = WallT;  N = 512;  rowoff = 512; }
    else if (bid < 3072) { bid -= 1024; W = Wqk_l; WT = WallT;  N = 2048; rowoff = 1024; }
    else if (bid < 3584) { bid -= 3072; W = Wv_l;  WT = WallT;  N = 512;  rowoff = 3072; }
    else                 { bid -= 3584; W = Wproj; WT = WprojT; N = 1024; rowoff = 0; }
    const int nt = N / 32;
    const int n0 = (bid % nt) * 32;
    const int k0 = (bid / nt) * 32;
    const int tx = threadIdx.x & 31;
    const int ty = threadIdx.x >> 5;  // 0..7
#pragma unroll
    for (int i = 0; i < 4; ++i)
        t[ty + 8 * i][tx] = W[(size_t)(k0 + ty + 8 * i) * N + n0 + tx];
    __syncthreads();
#pragma unroll
    for (int i = 0; i < 4; ++i)
        WT[(size_t)(rowoff + n0 + ty + 8 * i) * 1024 + k0 + tx] =
            f2bf(t[tx][ty + 8 * i]);
}

// ---------------------------------------------------------------------------
// bf16 MFMA GEMM: C[M,N] = A[M,K] bf16 @ BT[N,K] bf16.
// BM x 128 tile / 256 threads; BK=32, 16x16x32 MFMA; global_load_lds staging.
// ---------------------------------------------------------------------------
template <int BM, typename OT>
__global__ __launch_bounds__(256) void gemm_bf16(const ushort* __restrict__ A,
                                                 const ushort* __restrict__ BT,
                                                 OT* __restrict__ Cm,
                                                 int M, int N, int K) {
    __shared__ ushort As[BM * 32];
    __shared__ ushort Bs[128 * 32];
    constexpr int NI = BM / 32;
    const int tid = threadIdx.x;
    const int m0 = blockIdx.y * BM;
    const int n0 = blockIdx.x * 128;
    const int wave = tid >> 6;
    const int lane = tid & 63;
    const int wm = (wave >> 1) * (BM / 2);
    const int wn = (wave & 1) * 64;
    const int l15 = lane & 15;
    const int quad = lane >> 4;

    const int srow = tid >> 2;
    const int sc = (tid & 3) * 8;

    floatx4 acc[NI][4] = {};

    const ushort* Ap0 = A + (size_t)(m0 + srow) * K + sc;
    const ushort* Ap1 = A + (size_t)(m0 + (srow & 63) + 64) * K + sc;
    const ushort* Bp0 = BT + (size_t)(n0 + srow) * K + sc;
    const ushort* Bp1 = BT + (size_t)(n0 + srow + 64) * K + sc;

    ushort* AsB0 = &As[wave * 512];
    ushort* AsB1 = &As[(wave * 512 + 2048) % (BM * 32)];
    ushort* BsB0 = &Bs[wave * 512];
    ushort* BsB1 = &Bs[wave * 512 + 2048];

    for (int kt = 0; kt < K; kt += 32) {
        __syncthreads();
        gload_lds16(Ap0 + kt, AsB0);
        if constexpr (BM == 128) gload_lds16(Ap1 + kt, AsB1);
        gload_lds16(Bp0 + kt, BsB0);
        gload_lds16(Bp1 + kt, BsB1);
        __syncthreads();

        bf16x8 af[NI], bfr[4];
#pragma unroll
        for (int i = 0; i < NI; ++i)
            af[i] = *(const bf16x8*)&As[(wm + i * 16 + l15) * 32 + quad * 8];
#pragma unroll
        for (int j = 0; j < 4; ++j)
            bfr[j] = *(const bf16x8*)&Bs[(wn + j * 16 + l15) * 32 + quad * 8];
#pragma unroll
        for (int i = 0; i < NI; ++i)
#pragma unroll
            for (int j = 0; j < 4; ++j)
                acc[i][j] = __builtin_amdgcn_mfma_f32_16x16x32_bf16(
                    af[i], bfr[j], acc[i][j], 0, 0, 0);
    }

#pragma unroll
    for (int i = 0; i < NI; ++i)
#pragma unroll
        for (int j = 0; j < 4; ++j)
#pragma unroll
            for (int r = 0; r < 4; ++r) {
                const size_t idx = (size_t)(m0 + wm + i * 16 + quad * 4 + r) * N +
                                   n0 + wn + j * 16 + l15;
                if constexpr (sizeof(OT) == 2)
                    Cm[idx] = f2bf(acc[i][j][r]);
                else
                    Cm[idx] = acc[i][j][r];
            }
}

// ---------------------------------------------------------------------------
// V transpose: act V-columns -> vt[b][gh][d][T] (keys contiguous).
// ---------------------------------------------------------------------------
__global__ __launch_bounds__(256) void vtrans(const ushort* __restrict__ act,
                                              ushort* __restrict__ vt) {
    __shared__ ushort tile[64][72];
    const int t0 = blockIdx.x * 64;
    const int gh = blockIdx.y;
    const int b = blockIdx.z;
    const int col = (gh < 8) ? (512 + gh * 64) : (3072 + (gh - 8) * 64);
    const ushort* src = act + (size_t)(b * T_ + t0) * NALL_ + col;
    {
        const int tr = threadIdx.x >> 2;
        const int ch = threadIdx.x & 3;
        *(int4*)&tile[tr][ch * 8] =
            *(const int4*)(src + (size_t)tr * NALL_ + ch * 8);
        *(int4*)&tile[tr][(ch + 4) * 8] =
            *(const int4*)(src + (size_t)tr * NALL_ + (ch + 4) * 8);
    }
    __syncthreads();
    const int d = threadIdx.x >> 2;
    const int ts = (threadIdx.x & 3) * 16;
    ushort tmp[16];
#pragma unroll
    for (int i = 0; i < 16; ++i) tmp[i] = tile[ts + i][d];
    ushort* dst = vt + ((size_t)(b * 16 + gh) * HD_ + d) * T_ + t0 + ts;
    *(int4*)dst = *(int4*)tmp;
    *(int4*)(dst + 8) = *(int4*)(tmp + 8);
}

// ---------------------------------------------------------------------------
// MFMA flash attention, 128-query blocks (R10): each wave owns 32 query rows
// = two 16-row MFMA groups. K/V staged once per 64-key tile feed BOTH groups
// (1 ds_read -> 2 MFMAs in the S phase). 2-way K-split for long heads (bf16
// unnormalized o + fp32 m,l partials; flash-decoding combine). exp2-domain
// softmax (log2e folded into scale). LDS: Ks 64*(D+8) | VTs 64*72 | Ps 64*72
// = 35840 B (long). All-masked tiles/splits self-correct via rescale.
// ---------------------------------------------------------------------------
template <int D, int WIN, bool SPLIT>
__device__ __forceinline__ void attn_dev(
    const ushort* __restrict__ act, const ushort* __restrict__ vt,
    ushort* __restrict__ y, ushort* __restrict__ po, float* __restrict__ pm,
    float* __restrict__ pl, float scale2, int qoff, int koff, int head_off,
    int h, int gh, int b, int t0, int zs, ushort* lds) {
    constexpr int STR = D + 8;
    constexpr int PSTR = 72;
    constexpr int NKS = D / 32;
    constexpr int QCH = D / 8;
    constexpr int NKLD = (64 * QCH) / 256;

    ushort* Ks = lds;
    ushort* VTs = Ks + 64 * STR;
    ushort* Ps = VTs + 64 * PSTR;

    const int tid = threadIdx.x;
    const int wave = tid >> 6;
    const int lane = tid & 63;
    const int l15 = lane & 15;
    const int quad = lane >> 4;

    int k0s = t0 - WIN + 1;
    if (k0s < 0) k0s = 0;
    k0s &= ~63;
    const int ks_last_full = t0 + 64;  // last tile covers query t0+127

    int ks_begin = k0s, ks_last = ks_last_full;
    if (SPLIT) {
        const int nt = ((ks_last_full - k0s) >> 6) + 1;  // >= 2 always
        const int tb = (zs * nt) >> 1;
        const int te = ((zs + 1) * nt) >> 1;
        ks_begin = k0s + tb * 64;
        ks_last = k0s + (te - 1) * 64;
    }

    const ushort* qbase = act + (size_t)(b * T_ + t0) * NALL_ + qoff + h * D;
    const ushort* kbase = act + (size_t)(b * T_) * NALL_ + koff + h * D;
    const ushort* vtb = vt + (size_t)((b * 16 + gh) * HD_) * T_;

    int krow[NKLD], kch[NKLD];
#pragma unroll
    for (int i = 0; i < NKLD; ++i) {
        const int idx = tid + 256 * i;
        krow[i] = idx / QCH;
        kch[i] = idx % QCH;
    }
    const int vd0 = tid >> 3, vc0 = (tid & 7) * 8;
    const int vd1 = (tid + 256) >> 3, vc1 = ((tid + 256) & 7) * 8;

    // ---- prefetch first K/V tile into registers ----
    int4 kreg[NKLD], vreg0, vreg1;
#pragma unroll
    for (int i = 0; i < NKLD; ++i)
        kreg[i] = *(const int4*)(kbase + (size_t)(ks_begin + krow[i]) * NALL_ +
                                 kch[i] * 8);
    vreg0 = *(const int4*)(vtb + (size_t)vd0 * T_ + ks_begin + vc0);
    vreg1 = *(const int4*)(vtb + (size_t)vd1 * T_ + ks_begin + vc1);

    // ---- stage Q (128 rows) in two 64-row passes through Ks; hoist frags ----
    bf16x8 qa[2][NKS];
#pragma unroll
    for (int pass = 0; pass < 2; ++pass) {
        if (pass) __syncthreads();  // waves 0-1 done reading pass-A rows
        for (int idx = tid; idx < 64 * QCH; idx += 256) {
            const int row = idx / QCH;
            const int ch = idx % QCH;
            *(int4*)&Ks[row * STR + ch * 8] = *(const int4*)(
                qbase + (size_t)(pass * 64 + row) * NALL_ + ch * 8);
        }
        __syncthreads();
        if ((wave >> 1) == pass) {
#pragma unroll
            for (int g = 0; g < 2; ++g)
#pragma unroll
                for (int ks = 0; ks < NKS; ++ks)
                    qa[g][ks] = *(const bf16x8*)&Ks[((wave & 1) * 32 + g * 16 +
                                                     l15) * STR +
                                                    ks * 32 + quad * 8];
        }
    }

    float m_i[2][4], l_i[2][4];
    floatx4 o_acc[2][4] = {};
#pragma unroll
    for (int g = 0; g < 2; ++g)
#pragma unroll
        for (int r = 0; r < 4; ++r) { m_i[g][r] = -1e30f; l_i[g][r] = 0.f; }

    for (int k0 = ks_begin; k0 <= ks_last; k0 += 64) {
        __syncthreads();  // all waves done with Ks/VTs (incl. qa hoist)
#pragma unroll
        for (int i = 0; i < NKLD; ++i)
            *(int4*)&Ks[krow[i] * STR + kch[i] * 8] = kreg[i];
        *(int4*)&VTs[vd0 * PSTR + vc0] = vreg0;
        *(int4*)&VTs[vd1 * PSTR + vc1] = vreg1;
        __syncthreads();
        if (k0 + 64 <= ks_last) {  // prefetch next tile (overlaps compute)
#pragma unroll
            for (int i = 0; i < NKLD; ++i)
                kreg[i] = *(const int4*)(kbase +
                                         (size_t)(k0 + 64 + krow[i]) * NALL_ +
                                         kch[i] * 8);
            vreg0 = *(const int4*)(vtb + (size_t)vd0 * T_ + k0 + 64 + vc0);
            vreg1 = *(const int4*)(vtb + (size_t)vd1 * T_ + k0 + 64 + vc1);
        }

        // ---- S = Q K^T for both groups (shared K frag reads) ----
        floatx4 s[2][4] = {};
#pragma unroll
        for (int ks = 0; ks < NKS; ++ks) {
#pragma unroll
            for (int j = 0; j < 4; ++j) {
                const bf16x8 bb =
                    *(const bf16x8*)&Ks[(j * 16 + l15) * STR + ks * 32 + quad * 8];
                s[0][j] = __builtin_amdgcn_mfma_f32_16x16x32_bf16(qa[0][ks], bb,
                                                                  s[0][j], 0, 0, 0);
                s[1][j] = __builtin_amdgcn_mfma_f32_16x16x32_bf16(qa[1][ks], bb,
                                                                  s[1][j], 0, 0, 0);
            }
        }

#pragma unroll
        for (int g = 0; g < 2; ++g) {
            const int qmin = t0 + wave * 32 + g * 16;
            // ---- scale (log2 domain) + mask ----
            const bool full = (k0 + 63 <= qmin) && ((qmin + 15) - k0 <= WIN - 1);
            if (full) {
#pragma unroll
                for (int j = 0; j < 4; ++j)
#pragma unroll
                    for (int r = 0; r < 4; ++r) s[g][j][r] *= scale2;
            } else {
#pragma unroll
                for (int j = 0; j < 4; ++j) {
                    const int kj = k0 + j * 16 + l15;
#pragma unroll
                    for (int r = 0; r < 4; ++r) {
                        const int rel = (qmin + quad * 4 + r) - kj;
                        s[g][j][r] =
                            (rel < 0 || rel >= WIN) ? -1e30f : s[g][j][r] * scale2;
                    }
                }
            }

            // ---- online softmax (exp2 domain) ----
#pragma unroll
            for (int r = 0; r < 4; ++r) {
                float rm = fmaxf(fmaxf(s[g][0][r], s[g][1][r]),
                                 fmaxf(s[g][2][r], s[g][3][r]));
                rm = fmaxf(rm, __shfl_xor(rm, 1, 64));
                rm = fmaxf(rm, __shfl_xor(rm, 2, 64));
                rm = fmaxf(rm, __shfl_xor(rm, 4, 64));
                rm = fmaxf(rm, __shfl_xor(rm, 8, 64));
                const float mn = fmaxf(m_i[g][r], rm);
                const float a = exp2f(m_i[g][r] - mn);
                m_i[g][r] = mn;
                float sum = 0.f;
#pragma unroll
                for (int j = 0; j < 4; ++j) {
                    const float e = exp2f(s[g][j][r] - mn);
                    sum += e;
                    Ps[(wave * 16 + quad * 4 + r) * PSTR + j * 16 + l15] = f2bf(e);
                }
                sum += __shfl_xor(sum, 1, 64);
                sum += __shfl_xor(sum, 2, 64);
                sum += __shfl_xor(sum, 4, 64);
                sum += __shfl_xor(sum, 8, 64);
                l_i[g][r] = l_i[g][r] * a + sum;
#pragma unroll
                for (int j = 0; j < 4; ++j) o_acc[g][j][r] *= a;
            }

            // ---- PV for this group (Ps rows wave-private; same-wave order) ----
#pragma unroll
            for (int kks = 0; kks < 2; ++kks) {
                const bf16x8 pa = *(const bf16x8*)&Ps[(wave * 16 + l15) * PSTR +
                                                      kks * 32 + quad * 8];
#pragma unroll
                for (int j = 0; j < 4; ++j) {
                    const bf16x8 vb =
                        *(const bf16x8*)&VTs[(j * 16 + l15) * PSTR + kks * 32 +
                                             quad * 8];
                    o_acc[g][j] = __builtin_amdgcn_mfma_f32_16x16x32_bf16(
                        pa, vb, o_acc[g][j], 0, 0, 0);
                }
            }
        }
    }

    // ---- epilogue ----
#pragma unroll
    for (int g = 0; g < 2; ++g) {
        const int qmin = t0 + wave * 32 + g * 16;
        if (SPLIT) {
#pragma unroll
            for (int r = 0; r < 4; ++r) {
                const int t = qmin + quad * 4 + r;
                const size_t ridx = (((size_t)(zs * 2 + b) * 8 + h) * T_ + t);
                if (l15 == 0) { pm[ridx] = m_i[g][r]; pl[ridx] = l_i[g][r]; }
#pragma unroll
                for (int j = 0; j < 4; ++j)
                    po[ridx * 64 + j * 16 + l15] = f2bf(o_acc[g][j][r]);
            }
        } else {
#pragma unroll
            for (int r = 0; r < 4; ++r) {
                const float inv = 1.f / l_i[g][r];
                ushort* yrow = y + (size_t)(b * T_ + qmin + quad * 4 + r) * C_ +
                               head_off + h * HD_;
#pragma unroll
                for (int j = 0; j < 4; ++j)
                    yrow[j * 16 + l15] = f2bf(o_acc[g][j][r] * inv);
            }
        }
    }
}

// Sorted 1D job grid: x<512 = long 2-way splits (t0 desc), x>=512 = short
// unsplit (t0 desc). 768 blocks = 3/CU -> fully co-resident, no tail.
__global__ __launch_bounds__(256, 3) void attn_sched(
    const ushort* __restrict__ act, const ushort* __restrict__ vt,
    ushort* __restrict__ y, ushort* __restrict__ po, float* __restrict__ pm,
    float* __restrict__ pl) {
    extern __shared__ ushort smem[];
    int x = blockIdx.x;
    if (x < 512) {
        const int zs = x & 1;
        const int b = (x >> 1) & 1;
        const int h = (x >> 2) & 7;
        const int t0 = (15 - (x >> 5)) * 128;
        attn_dev<DL_, WINL_, true>(act, vt, y, po, pm, pl,
                                   0.12752021352994164f,  // 1/sqrt(128)*log2e
                                   1024, 2048, 512, h, 8 + h, b, t0, zs, smem);
    } else {
        x -= 512;
        const int b = x & 1;
        const int h = (x >> 1) & 7;
        const int t0 = (15 - (x >> 4)) * 128;
        attn_dev<DS_, WINS_, false>(act, vt, y, po, pm, pl,
                                    0.2550404270598833f,  // 1/sqrt(32)*log2e
                                    0, 256, 0, h, h, b, t0, 0, smem);
    }
}

// ---------------------------------------------------------------------------
// Flash-decoding combine for long heads: merge 2 splits' (o,m,l) -> yb16.
// exp2 domain (matches attn). rows = [b][h][t]; thread = one row x 4 cols.
// ---------------------------------------------------------------------------
__global__ __launch_bounds__(256) void combine(const ushort* __restrict__ po,
                                               const float* __restrict__ pm,
                                               const float* __restrict__ pl,
                                               ushort* __restrict__ y) {
    const int gid = blockIdx.x * 256 + threadIdx.x;
    const int row = gid >> 4;
    const int cg = (gid & 15) * 4;
    const int b = row >> 14;
    const int h = (row >> 11) & 7;
    const int t = row & 2047;

    const float m0 = pm[row], m1 = pm[32768 + row];
    const float l0 = pl[row], l1 = pl[32768 + row];
    const float m = fmaxf(m0, m1);
    const float e0 = exp2f(m0 - m);
    const float e1 = exp2f(m1 - m);
    const float inv = 1.f / (l0 * e0 + l1 * e1);

    const ushort4 o0 = *(const ushort4*)&po[(size_t)row * 64 + cg];
    const ushort4 o1 = *(const ushort4*)&po[((size_t)32768 + row) * 64 + cg];

    ushort4 r;
    r.x = f2bf((bf2f(o0.x) * e0 + bf2f(o1.x) * e1) * inv);
    r.y = f2bf((bf2f(o0.y) * e0 + bf2f(o1.y) * e1) * inv);
    r.z = f2bf((bf2f(o0.z) * e0 + bf2f(o1.z) * e1) * inv);
    r.w = f2bf((bf2f(o0.w) * e0 + bf2f(o1.w) * e1) * inv);
    *(ushort4*)&y[(size_t)(b * T_ + t) * C_ + 512 + h * 64 + cg] = r;
}

// ---------------------------------------------------------------------------
extern "C" void kernel_launch(void* const* d_in, const int* in_sizes, int n_in,
                              void* d_out, int out_size, void* d_ws,
                              size_t ws_size, hipStream_t stream) {
    const float* x         = (const float*)d_in[0];
    const float* Wqk_short = (const float*)d_in[1];
    const float* Wv_short  = (const float*)d_in[2];
    const float* Wqk_long  = (const float*)d_in[3];
    const float* Wv_long   = (const float*)d_in[4];
    const float* Wproj     = (const float*)d_in[5];
    float* out = (float*)d_out;

    const int M = B_ * T_;  // 4096

    // workspace layout (~75 MB)
    ushort* x16    = (ushort*)d_ws;                 // [4096][1024] bf16
    ushort* WallT  = x16 + (size_t)M * C_;          // [3584][1024] bf16
    ushort* WprojT = WallT + (size_t)NALL_ * C_;    // [1024][1024] bf16
    ushort* yb16   = WprojT + (size_t)C_ * C_;      // [4096][1024] bf16
    ushort* act    = yb16 + (size_t)M * C_;         // [4096][3584] bf16
    ushort* vt     = act + (size_t)M * NALL_;       // [32][64][2048] bf16
    ushort* po     = vt + (size_t)32 * HD_ * T_;    // [2][2][8][2048][64] bf16
    float*  pm     = (float*)(po + (size_t)2 * 32768 * 64);  // [2][32768]
    float*  pl     = pm + (size_t)2 * 32768;                 // [2][32768]

    dim3 blk(256);
    prep<<<dim3(8704), blk, 0, stream>>>(x, x16, Wqk_short, Wv_short, Wqk_long,
                                         Wv_long, Wproj, WallT, WprojT);

    gemm_bf16<128, ushort><<<dim3(NALL_ / 128, M / 128), blk, 0, stream>>>(
        x16, WallT, act, M, NALL_, C_);

    vtrans<<<dim3(T_ / 64, 16, B_), blk, 0, stream>>>(act, vt);

    const int attn_lds = (64 * (DL_ + 8) + 64 * 72 * 2) * 2;  // 35840 B
    attn_sched<<<dim3(768), blk, attn_lds, stream>>>(act, vt, yb16, po, pm, pl);

    combine<<<dim3(2048), blk, 0, stream>>>(po, pm, pl, yb16);

    gemm_bf16<64, float><<<dim3(C_ / 128, M / 64), blk, 0, stream>>>(
        yb16, WprojT, out, M, C_, C_);
}

// Round 12
// 228.358 us; speedup vs baseline: 1.2037x; 1.2037x over previous
//
#include <hip/hip_runtime.h>
#include <math.h>

// Problem constants (match reference)
#define B_    2
#define T_    2048
#define C_    1024
#define HS_   8
#define DS_   32
#define HL_   8
#define DL_   128
#define HD_   64
#define WINS_ 256
#define WINL_ 1024
#define NALL_ 3584   // 512 (qk_s) + 512 (v_s) + 2048 (qk_l) + 512 (v_l)

typedef __bf16 bf16x8 __attribute__((ext_vector_type(8)));
typedef float floatx4 __attribute__((ext_vector_type(4)));

__device__ __forceinline__ ushort f2bf(float f) {
    union { float f; unsigned u; } v; v.f = f;
    unsigned r = v.u + 0x7fff + ((v.u >> 16) & 1);  // RNE
    return (ushort)(r >> 16);
}
__device__ __forceinline__ float bf2f(ushort u) {
    union { unsigned u; float f; } v; v.u = ((unsigned)u) << 16;
    return v.f;
}

// async global->LDS, 16B per lane. LDS dest = wave-uniform base + lane*16.
__device__ __forceinline__ void gload_lds16(const void* g, void* l) {
    __builtin_amdgcn_global_load_lds(
        (const __attribute__((address_space(1))) void*)g,
        (__attribute__((address_space(3))) void*)l, 16, 0, 0);
}

// ---------------------------------------------------------------------------
// Fused prep: blocks [0,4096) convert x fp32->bf16; blocks [4096,8704)
// transpose+convert the five weight matrices (K=1024 each).
// ---------------------------------------------------------------------------
__global__ __launch_bounds__(256) void prep(
    const float* __restrict__ x, ushort* __restrict__ x16,
    const float* __restrict__ Wqk_s, const float* __restrict__ Wv_s,
    const float* __restrict__ Wqk_l, const float* __restrict__ Wv_l,
    const float* __restrict__ Wproj, ushort* __restrict__ WallT,
    ushort* __restrict__ WprojT) {
    __shared__ float t[32][33];
    int bid = blockIdx.x;
    if (bid < 4096) {
        const int i = bid * 256 + threadIdx.x;
        float4 v = ((const float4*)x)[i];
        ushort4 o;
        o.x = f2bf(v.x); o.y = f2bf(v.y); o.z = f2bf(v.z); o.w = f2bf(v.w);
        ((ushort4*)x16)[i] = o;
        return;
    }
    bid -= 4096;
    const float* W; ushort* WT; int N, rowoff;
    if (bid < 512)       { W = Wqk_s; WT = WallT;  N = 512;  rowoff = 0; }
    else if (bid < 1024) { bid -= 512;  W = Wv_s;  WT = WallT;  N = 512;  rowoff = 512; }
    else if (bid < 3072) { bid -= 1024; W = Wqk_l; WT = WallT;  N = 2048; rowoff = 1024; }
    else if (bid < 3584) { bid -= 3072; W = Wv_l;  WT = WallT;  N = 512;  rowoff = 3072; }
    else                 { bid -= 3584; W = Wproj; WT = WprojT; N = 1024; rowoff = 0; }
    const int nt = N / 32;
    const int n0 = (bid % nt) * 32;
    const int k0 = (bid / nt) * 32;
    const int tx = threadIdx.x & 31;
    const int ty = threadIdx.x >> 5;  // 0..7
#pragma unroll
    for (int i = 0; i < 4; ++i)
        t[ty + 8 * i][tx] = W[(size_t)(k0 + ty + 8 * i) * N + n0 + tx];
    __syncthreads();
#pragma unroll
    for (int i = 0; i < 4; ++i)
        WT[(size_t)(rowoff + n0 + ty + 8 * i) * 1024 + k0 + tx] =
            f2bf(t[tx][ty + 8 * i]);
}

// ---------------------------------------------------------------------------
// bf16 MFMA GEMM: C[M,N] = A[M,K] bf16 @ BT[N,K] bf16.
// BM x 128 tile / 256 threads; BK=32, 16x16x32 MFMA; global_load_lds staging.
// BM=128 for the fused input projection; BM=64 for Wproj (512 blocks = 2/CU).
// ---------------------------------------------------------------------------
template <int BM, typename OT>
__global__ __launch_bounds__(256) void gemm_bf16(const ushort* __restrict__ A,
                                                 const ushort* __restrict__ BT,
                                                 OT* __restrict__ Cm,
                                                 int M, int N, int K) {
    __shared__ ushort As[BM * 32];
    __shared__ ushort Bs[128 * 32];
    constexpr int NI = BM / 32;
    const int tid = threadIdx.x;
    const int m0 = blockIdx.y * BM;
    const int n0 = blockIdx.x * 128;
    const int wave = tid >> 6;
    const int lane = tid & 63;
    const int wm = (wave >> 1) * (BM / 2);
    const int wn = (wave & 1) * 64;
    const int l15 = lane & 15;
    const int quad = lane >> 4;

    const int srow = tid >> 2;
    const int sc = (tid & 3) * 8;

    floatx4 acc[NI][4] = {};

    const ushort* Ap0 = A + (size_t)(m0 + srow) * K + sc;
    const ushort* Ap1 = A + (size_t)(m0 + (srow & 63) + 64) * K + sc;
    const ushort* Bp0 = BT + (size_t)(n0 + srow) * K + sc;
    const ushort* Bp1 = BT + (size_t)(n0 + srow + 64) * K + sc;

    ushort* AsB0 = &As[wave * 512];
    ushort* AsB1 = &As[(wave * 512 + 2048) % (BM * 32)];
    ushort* BsB0 = &Bs[wave * 512];
    ushort* BsB1 = &Bs[wave * 512 + 2048];

    for (int kt = 0; kt < K; kt += 32) {
        __syncthreads();
        gload_lds16(Ap0 + kt, AsB0);
        if constexpr (BM == 128) gload_lds16(Ap1 + kt, AsB1);
        gload_lds16(Bp0 + kt, BsB0);
        gload_lds16(Bp1 + kt, BsB1);
        __syncthreads();

        bf16x8 af[NI], bfr[4];
#pragma unroll
        for (int i = 0; i < NI; ++i)
            af[i] = *(const bf16x8*)&As[(wm + i * 16 + l15) * 32 + quad * 8];
#pragma unroll
        for (int j = 0; j < 4; ++j)
            bfr[j] = *(const bf16x8*)&Bs[(wn + j * 16 + l15) * 32 + quad * 8];
#pragma unroll
        for (int i = 0; i < NI; ++i)
#pragma unroll
            for (int j = 0; j < 4; ++j)
                acc[i][j] = __builtin_amdgcn_mfma_f32_16x16x32_bf16(
                    af[i], bfr[j], acc[i][j], 0, 0, 0);
    }

#pragma unroll
    for (int i = 0; i < NI; ++i)
#pragma unroll
        for (int j = 0; j < 4; ++j)
#pragma unroll
            for (int r = 0; r < 4; ++r) {
                const size_t idx = (size_t)(m0 + wm + i * 16 + quad * 4 + r) * N +
                                   n0 + wn + j * 16 + l15;
                if constexpr (sizeof(OT) == 2)
                    Cm[idx] = f2bf(acc[i][j][r]);
                else
                    Cm[idx] = acc[i][j][r];
            }
}

// ---------------------------------------------------------------------------
// V transpose: act V-columns -> vt[b][gh][d][T] (keys contiguous).
// ---------------------------------------------------------------------------
__global__ __launch_bounds__(256) void vtrans(const ushort* __restrict__ act,
                                              ushort* __restrict__ vt) {
    __shared__ ushort tile[64][72];
    const int t0 = blockIdx.x * 64;
    const int gh = blockIdx.y;
    const int b = blockIdx.z;
    const int col = (gh < 8) ? (512 + gh * 64) : (3072 + (gh - 8) * 64);
    const ushort* src = act + (size_t)(b * T_ + t0) * NALL_ + col;
    {
        const int tr = threadIdx.x >> 2;
        const int ch = threadIdx.x & 3;
        *(int4*)&tile[tr][ch * 8] =
            *(const int4*)(src + (size_t)tr * NALL_ + ch * 8);
        *(int4*)&tile[tr][(ch + 4) * 8] =
            *(const int4*)(src + (size_t)tr * NALL_ + (ch + 4) * 8);
    }
    __syncthreads();
    const int d = threadIdx.x >> 2;
    const int ts = (threadIdx.x & 3) * 16;
    ushort tmp[16];
#pragma unroll
    for (int i = 0; i < 16; ++i) tmp[i] = tile[ts + i][d];
    ushort* dst = vt + ((size_t)(b * 16 + gh) * HD_ + d) * T_ + t0 + ts;
    *(int4*)dst = *(int4*)tmp;
    *(int4*)(dst + 8) = *(int4*)(tmp + 8);
}

// ---------------------------------------------------------------------------
// MFMA flash attention core — R8/R9 structure EXACT (the 60 µs config):
// 64-query blocks, LDS-shared K/V, reg-prefetch pipeline, 2-way K-split for
// long heads. Partials: bf16 unnormalized o + fp32 (m,l). exp2-domain
// softmax (log2e folded into scale). All-masked tiles/splits self-correct
// via the online rescale (e^(m_i - m) = 0).
// LDS: Ks 64*(D+8) | VTs 64*72 | Ps 64*72 -> long 35840 B => 4 blocks/CU.
// ---------------------------------------------------------------------------
template <int D, int WIN, bool SPLIT>
__device__ __forceinline__ void attn_dev(
    const ushort* __restrict__ act, const ushort* __restrict__ vt,
    ushort* __restrict__ y, ushort* __restrict__ po, float* __restrict__ pm,
    float* __restrict__ pl, float scale2, int qoff, int koff, int head_off,
    int h, int gh, int b, int t0, int zs, ushort* lds) {
    constexpr int STR = D + 8;
    constexpr int PSTR = 72;
    constexpr int NKS = D / 32;
    constexpr int QCH = D / 8;
    constexpr int NKLD = (64 * QCH) / 256;

    ushort* Ks = lds;
    ushort* VTs = Ks + 64 * STR;
    ushort* Ps = VTs + 64 * PSTR;

    const int tid = threadIdx.x;
    const int wave = tid >> 6;
    const int lane = tid & 63;
    const int l15 = lane & 15;
    const int quad = lane >> 4;
    const int qmin = t0 + wave * 16;

    int k0s = t0 - WIN + 1;
    if (k0s < 0) k0s = 0;
    k0s &= ~63;

    int ks_begin = k0s, ks_last = t0;
    if (SPLIT) {
        const int nt = ((t0 - k0s) >> 6) + 1;
        const int ntlo = (nt + 1) >> 1;
        if (zs == 0) {
            ks_last = k0s + (ntlo - 1) * 64;
        } else {
            if (ntlo >= nt) {  // empty split: zero partials, done
#pragma unroll
                for (int r = 0; r < 4; ++r) {
                    const int t = qmin + quad * 4 + r;
                    const size_t ridx =
                        (((size_t)(zs * 2 + b) * 8 + h) * T_ + t);
                    if (l15 == 0) { pm[ridx] = -1e30f; pl[ridx] = 0.f; }
#pragma unroll
                    for (int j = 0; j < 4; ++j)
                        po[ridx * 64 + j * 16 + l15] = 0;
                }
                return;
            }
            ks_begin = k0s + ntlo * 64;
        }
    }

    const ushort* qbase = act + (size_t)(b * T_ + t0) * NALL_ + qoff + h * D;
    const ushort* kbase = act + (size_t)(b * T_) * NALL_ + koff + h * D;
    const ushort* vtb = vt + (size_t)((b * 16 + gh) * HD_) * T_;

    int krow[NKLD], kch[NKLD];
#pragma unroll
    for (int i = 0; i < NKLD; ++i) {
        const int idx = tid + 256 * i;
        krow[i] = idx / QCH;
        kch[i] = idx % QCH;
    }
    const int vd0 = tid >> 3, vc0 = (tid & 7) * 8;
    const int vd1 = (tid + 256) >> 3, vc1 = ((tid + 256) & 7) * 8;

    // ---- prefetch first tile into registers ----
    int4 kreg[NKLD], vreg0, vreg1;
#pragma unroll
    for (int i = 0; i < NKLD; ++i)
        kreg[i] = *(const int4*)(kbase + (size_t)(ks_begin + krow[i]) * NALL_ +
                                 kch[i] * 8);
    vreg0 = *(const int4*)(vtb + (size_t)vd0 * T_ + ks_begin + vc0);
    vreg1 = *(const int4*)(vtb + (size_t)vd1 * T_ + ks_begin + vc1);

    // ---- stage Q once (through Ks), hoist frags to registers ----
    for (int idx = tid; idx < 64 * QCH; idx += 256) {
        const int row = idx / QCH;
        const int ch = idx % QCH;
        *(int4*)&Ks[row * STR + ch * 8] =
            *(const int4*)(qbase + (size_t)row * NALL_ + ch * 8);
    }
    __syncthreads();
    bf16x8 qa[NKS];
#pragma unroll
    for (int ks = 0; ks < NKS; ++ks)
        qa[ks] = *(const bf16x8*)&Ks[(wave * 16 + l15) * STR + ks * 32 + quad * 8];

    float m_i[4], l_i[4];
    floatx4 o_acc[4] = {};
#pragma unroll
    for (int r = 0; r < 4; ++r) { m_i[r] = -1e30f; l_i[r] = 0.f; }

    for (int k0 = ks_begin; k0 <= ks_last; k0 += 64) {
        __syncthreads();  // all waves done with Ks (incl. qa) / VTs
#pragma unroll
        for (int i = 0; i < NKLD; ++i)
            *(int4*)&Ks[krow[i] * STR + kch[i] * 8] = kreg[i];
        *(int4*)&VTs[vd0 * PSTR + vc0] = vreg0;
        *(int4*)&VTs[vd1 * PSTR + vc1] = vreg1;
        __syncthreads();
        if (k0 + 64 <= ks_last) {  // prefetch next tile (overlaps compute)
#pragma unroll
            for (int i = 0; i < NKLD; ++i)
                kreg[i] = *(const int4*)(kbase +
                                         (size_t)(k0 + 64 + krow[i]) * NALL_ +
                                         kch[i] * 8);
            vreg0 = *(const int4*)(vtb + (size_t)vd0 * T_ + k0 + 64 + vc0);
            vreg1 = *(const int4*)(vtb + (size_t)vd1 * T_ + k0 + 64 + vc1);
        }

        // ---- S = Q K^T ----
        floatx4 s[4] = {};
#pragma unroll
        for (int ks = 0; ks < NKS; ++ks) {
#pragma unroll
            for (int j = 0; j < 4; ++j) {
                const bf16x8 bb =
                    *(const bf16x8*)&Ks[(j * 16 + l15) * STR + ks * 32 + quad * 8];
                s[j] = __builtin_amdgcn_mfma_f32_16x16x32_bf16(qa[ks], bb, s[j],
                                                               0, 0, 0);
            }
        }

        // ---- scale (log2 domain) + mask ----
        const bool full = (k0 + 63 <= qmin) && ((qmin + 15) - k0 <= WIN - 1);
        if (full) {
#pragma unroll
            for (int j = 0; j < 4; ++j)
#pragma unroll
                for (int r = 0; r < 4; ++r) s[j][r] *= scale2;
        } else {
#pragma unroll
            for (int j = 0; j < 4; ++j) {
                const int kj = k0 + j * 16 + l15;
#pragma unroll
                for (int r = 0; r < 4; ++r) {
                    const int rel = (qmin + quad * 4 + r) - kj;
                    s[j][r] = (rel < 0 || rel >= WIN) ? -1e30f : s[j][r] * scale2;
                }
            }
        }

        // ---- online softmax (exp2 domain) ----
#pragma unroll
        for (int r = 0; r < 4; ++r) {
            float rm = fmaxf(fmaxf(s[0][r], s[1][r]), fmaxf(s[2][r], s[3][r]));
            rm = fmaxf(rm, __shfl_xor(rm, 1, 64));
            rm = fmaxf(rm, __shfl_xor(rm, 2, 64));
            rm = fmaxf(rm, __shfl_xor(rm, 4, 64));
            rm = fmaxf(rm, __shfl_xor(rm, 8, 64));
            const float mn = fmaxf(m_i[r], rm);
            const float a = exp2f(m_i[r] - mn);
            m_i[r] = mn;
            float sum = 0.f;
#pragma unroll
            for (int j = 0; j < 4; ++j) {
                const float e = exp2f(s[j][r] - mn);
                sum += e;
                Ps[(wave * 16 + quad * 4 + r) * PSTR + j * 16 + l15] = f2bf(e);
            }
            sum += __shfl_xor(sum, 1, 64);
            sum += __shfl_xor(sum, 2, 64);
            sum += __shfl_xor(sum, 4, 64);
            sum += __shfl_xor(sum, 8, 64);
            l_i[r] = l_i[r] * a + sum;
#pragma unroll
            for (int j = 0; j < 4; ++j) o_acc[j][r] *= a;
        }

        // ---- PV ----
#pragma unroll
        for (int kks = 0; kks < 2; ++kks) {
            const bf16x8 pa =
                *(const bf16x8*)&Ps[(wave * 16 + l15) * PSTR + kks * 32 + quad * 8];
#pragma unroll
            for (int j = 0; j < 4; ++j) {
                const bf16x8 vb =
                    *(const bf16x8*)&VTs[(j * 16 + l15) * PSTR + kks * 32 + quad * 8];
                o_acc[j] = __builtin_amdgcn_mfma_f32_16x16x32_bf16(pa, vb, o_acc[j],
                                                                   0, 0, 0);
            }
        }
    }

    // ---- epilogue ----
    if (SPLIT) {
#pragma unroll
        for (int r = 0; r < 4; ++r) {
            const int t = qmin + quad * 4 + r;
            const size_t ridx = (((size_t)(zs * 2 + b) * 8 + h) * T_ + t);
            if (l15 == 0) { pm[ridx] = m_i[r]; pl[ridx] = l_i[r]; }
#pragma unroll
            for (int j = 0; j < 4; ++j)
                po[ridx * 64 + j * 16 + l15] = f2bf(o_acc[j][r]);
        }
    } else {
#pragma unroll
        for (int r = 0; r < 4; ++r) {
            const float inv = 1.f / l_i[r];
            ushort* yrow = y + (size_t)(b * T_ + qmin + quad * 4 + r) * C_ +
                           head_off + h * HD_;
#pragma unroll
            for (int j = 0; j < 4; ++j)
                yrow[j * 16 + l15] = f2bf(o_acc[j][r] * inv);
        }
    }
}

// Sorted 1D job grid (R8 mapping): x<1024 = long 2-way splits (t0 desc),
// x>=1024 = short unsplit (t0 desc). 1536 blocks, heavy first.
__global__ __launch_bounds__(256, 4) void attn_sched(
    const ushort* __restrict__ act, const ushort* __restrict__ vt,
    ushort* __restrict__ y, ushort* __restrict__ po, float* __restrict__ pm,
    float* __restrict__ pl) {
    extern __shared__ ushort smem[];
    int x = blockIdx.x;
    if (x < 1024) {
        const int zs = x & 1;
        const int b = (x >> 1) & 1;
        const int h = (x >> 2) & 7;
        const int t0 = (31 - (x >> 5)) * 64;
        attn_dev<DL_, WINL_, true>(act, vt, y, po, pm, pl,
                                   0.12752021352994164f,  // 1/sqrt(128)*log2e
                                   1024, 2048, 512, h, 8 + h, b, t0, zs, smem);
    } else {
        x -= 1024;
        const int b = x & 1;
        const int h = (x >> 1) & 7;
        const int t0 = (31 - (x >> 4)) * 64;
        attn_dev<DS_, WINS_, false>(act, vt, y, po, pm, pl,
                                    0.2550404270598833f,  // 1/sqrt(32)*log2e
                                    0, 256, 0, h, h, b, t0, 0, smem);
    }
}

// ---------------------------------------------------------------------------
// Flash-decoding combine for long heads: merge 2 splits' (o,m,l) -> yb16.
// exp2 domain. rows = [b][h][t] (32768); thread = one row x 4 cols.
// ---------------------------------------------------------------------------
__global__ __launch_bounds__(256) void combine(const ushort* __restrict__ po,
                                               const float* __restrict__ pm,
                                               const float* __restrict__ pl,
                                               ushort* __restrict__ y) {
    const int gid = blockIdx.x * 256 + threadIdx.x;
    const int row = gid >> 4;
    const int cg = (gid & 15) * 4;
    const int b = row >> 14;
    const int h = (row >> 11) & 7;
    const int t = row & 2047;

    const float m0 = pm[row], m1 = pm[32768 + row];
    const float l0 = pl[row], l1 = pl[32768 + row];
    const float m = fmaxf(m0, m1);
    const float e0 = exp2f(m0 - m);
    const float e1 = exp2f(m1 - m);
    const float inv = 1.f / (l0 * e0 + l1 * e1);

    const ushort4 o0 = *(const ushort4*)&po[(size_t)row * 64 + cg];
    const ushort4 o1 = *(const ushort4*)&po[((size_t)32768 + row) * 64 + cg];

    ushort4 r;
    r.x = f2bf((bf2f(o0.x) * e0 + bf2f(o1.x) * e1) * inv);
    r.y = f2bf((bf2f(o0.y) * e0 + bf2f(o1.y) * e1) * inv);
    r.z = f2bf((bf2f(o0.z) * e0 + bf2f(o1.z) * e1) * inv);
    r.w = f2bf((bf2f(o0.w) * e0 + bf2f(o1.w) * e1) * inv);
    *(ushort4*)&y[(size_t)(b * T_ + t) * C_ + 512 + h * 64 + cg] = r;
}

// ---------------------------------------------------------------------------
extern "C" void kernel_launch(void* const* d_in, const int* in_sizes, int n_in,
                              void* d_out, int out_size, void* d_ws,
                              size_t ws_size, hipStream_t stream) {
    const float* x         = (const float*)d_in[0];
    const float* Wqk_short = (const float*)d_in[1];
    const float* Wv_short  = (const float*)d_in[2];
    const float* Wqk_long  = (const float*)d_in[3];
    const float* Wv_long   = (const float*)d_in[4];
    const float* Wproj     = (const float*)d_in[5];
    float* out = (float*)d_out;

    const int M = B_ * T_;  // 4096

    // workspace layout (~75 MB)
    ushort* x16    = (ushort*)d_ws;                 // [4096][1024] bf16
    ushort* WallT  = x16 + (size_t)M * C_;          // [3584][1024] bf16
    ushort* WprojT = WallT + (size_t)NALL_ * C_;    // [1024][1024] bf16
    ushort* yb16   = WprojT + (size_t)C_ * C_;      // [4096][1024] bf16
    ushort* act    = yb16 + (size_t)M * C_;         // [4096][3584] bf16
    ushort* vt     = act + (size_t)M * NALL_;       // [32][64][2048] bf16
    ushort* po     = vt + (size_t)32 * HD_ * T_;    // [2][2][8][2048][64] bf16
    float*  pm     = (float*)(po + (size_t)2 * 32768 * 64);  // [2][32768]
    float*  pl     = pm + (size_t)2 * 32768;                 // [2][32768]

    dim3 blk(256);
    prep<<<dim3(8704), blk, 0, stream>>>(x, x16, Wqk_short, Wv_short, Wqk_long,
                                         Wv_long, Wproj, WallT, WprojT);

    gemm_bf16<128, ushort><<<dim3(NALL_ / 128, M / 128), blk, 0, stream>>>(
        x16, WallT, act, M, NALL_, C_);

    vtrans<<<dim3(T_ / 64, 16, B_), blk, 0, stream>>>(act, vt);

    const int attn_lds = (64 * (DL_ + 8) + 64 * 72 * 2) * 2;  // 35840 B
    attn_sched<<<dim3(1536), blk, attn_lds, stream>>>(act, vt, yb16, po, pm, pl);

    combine<<<dim3(2048), blk, 0, stream>>>(po, pm, pl, yb16);

    gemm_bf16<64, float><<<dim3(C_ / 128, M / 64), blk, 0, stream>>>(
        yb16, WprojT, out, M, C_, C_);
}